// Round 6
// baseline (256.922 us; speedup 1.0000x reference)
//
#include <hip/hip_runtime.h>

#define HW   (256*256)        // 65536
#define VOL  (64*HW)          // 4194304 per batch volume
#define NTOT (4ull*VOL)
#define C1v  1e-4f
#define C2v  9e-4f
#define EPSv 1e-8f

typedef float    f2 __attribute__((ext_vector_type(2)));
typedef _Float16 h2 __attribute__((ext_vector_type(2)));
typedef _Float16 h4 __attribute__((ext_vector_type(4)));

// ws layout:
// [0      .. 63]     : w[11] float (1D separable weights)
// [64     .. 16447]  : partials[2048] double
// [16640  .. ]       : packed field volumes, 10 bytes/element per batch:
//                      F0 = h2{X,Y}[VOL], F1 = h2{XX,YY}[VOL], F2 = f16 XY[VOL]

__global__ void init_weights(const float* __restrict__ k3, float* __restrict__ w) {
    int i = threadIdx.x;
    if (i < 11) {
        float s = 0.f;
        for (int t = 0; t < 121; ++t) s += k3[i * 121 + t];
        w[i] = s;   // k3 is separable: row-sum = 1D weight
    }
}

// Pass 1: stage-time products (packed fp16) + W-conv (pk_fma) + H-conv (pk_fma).
// grid: (4, 16, 64*nb) x 256. Tile = 16(h) x 64(w) of one d-slice.
__global__ __launch_bounds__(256) void blur_hw(
    const float* __restrict__ x, const float* __restrict__ y,
    const float* __restrict__ w11, char* __restrict__ fields, int b0)
{
    __shared__ h2 P0[26][74];        // {x,y}    7,696 B
    __shared__ h2 P1[26][74];        // {xx,yy}  7,696 B
    __shared__ _Float16 P2[26][74];  // xy       3,848 B
    __shared__ h2 T0[26][64];        // {X,Y}    6,656 B
    __shared__ h2 T1[26][64];        // {XX,YY}  6,656 B
    __shared__ _Float16 T2[26][64];  // XY       3,328 B   -> 35,880 B total

    const int d   = blockIdx.z & 63;
    const int bz  = blockIdx.z >> 6;
    const int h0  = blockIdx.y * 16;
    const int w0  = blockIdx.x * 64;
    const int tid = threadIdx.x;

    h2 wl2[11];
    _Float16 wlh[11];
#pragma unroll
    for (int t = 0; t < 11; ++t) {
        _Float16 h = (_Float16)w11[t];
        wl2[t] = (h2){h, h};
        wlh[t] = h;
    }

    const float* xb = x + (size_t)(b0 + bz) * VOL + (size_t)d * HW;
    const float* yb = y + (size_t)(b0 + bz) * VOL + (size_t)d * HW;

    // stage halo tile 26 x 74 with products computed once
    for (int p = tid; p < 26 * 74; p += 256) {
        int r = p / 74, c = p - r * 74;
        int gh = h0 - 5 + r, gw = w0 - 5 + c;
        float xv = 0.f, yv = 0.f;
        if (((unsigned)gh < 256u) && ((unsigned)gw < 256u)) {
            xv = xb[gh * 256 + gw];
            yv = yb[gh * 256 + gw];
        }
        P0[r][c] = (h2){(_Float16)xv, (_Float16)yv};
        P1[r][c] = (h2){(_Float16)(xv * xv), (_Float16)(yv * yv)};
        P2[r][c] = (_Float16)(xv * yv);
    }
    __syncthreads();

    // W-conv: rows strided by wave (uniform per-wave trip count), packed fp16 math
    {
        const int wid = tid >> 6, lane = tid & 63;
        for (int r = wid; r < 26; r += 4) {
            h2 a0 = {0, 0}, a1 = {0, 0};
            _Float16 axy = (_Float16)0;
#pragma unroll
            for (int k = 0; k < 11; ++k) {
                a0  += wl2[k] * P0[r][lane + k];
                a1  += wl2[k] * P1[r][lane + k];
                axy += wlh[k] * P2[r][lane + k];
            }
            T0[r][lane] = a0;
            T1[r][lane] = a1;
            T2[r][lane] = axy;
        }
    }
    __syncthreads();

    h2* F0 = (h2*)(fields + (size_t)bz * 10 * VOL);
    h2* F1 = F0 + (size_t)VOL;
    _Float16* F2 = (_Float16*)(F1 + (size_t)VOL);

    // H-conv: thread owns element pairs (2tid,2tid+1) and (512+2tid, +1); b64 tap reads
#pragma unroll
    for (int i = 0; i < 2; ++i) {
        int e = 2 * tid + 512 * i;          // element in 16x64 tile, even
        int r = e >> 6, c = e & 63;         // c even
        h2 o0a = {0,0}, o0b = {0,0}, o1a = {0,0}, o1b = {0,0}, oxy = {0,0};
#pragma unroll
        for (int j = 0; j < 11; ++j) {
            h2 w2 = wl2[j];
            h4 t0p = *(const h4*)&T0[r + j][c];
            h4 t1p = *(const h4*)&T1[r + j][c];
            h2 t2p = *(const h2*)&T2[r + j][c];
            h2 t0lo = {t0p[0], t0p[1]}, t0hi = {t0p[2], t0p[3]};
            h2 t1lo = {t1p[0], t1p[1]}, t1hi = {t1p[2], t1p[3]};
            o0a += w2 * t0lo;  o0b += w2 * t0hi;
            o1a += w2 * t1lo;  o1b += w2 * t1hi;
            oxy += w2 * t2p;
        }
        size_t oi = (size_t)d * HW + (size_t)(h0 + r) * 256 + (w0 + c);
        F0[oi]     = o0a;
        F0[oi + 1] = o0b;
        F1[oi]     = o1a;
        F1[oi + 1] = o1b;
        *(h2*)&F2[oi] = oxy;
    }
}

// Pass 2: D-conv via scalar fp32 register rings, packed field loads.
// DHALF compile-time so ALL guards fold; grid: (256, nb) x 256.
template<int DHALF>
__global__ __launch_bounds__(256) void dconv_ssim(
    const char* __restrict__ fields, const float* __restrict__ w11,
    double* __restrict__ partials, int b0)
{
    const int col = blockIdx.x * 256 + threadIdx.x;  // 0..65535 within slice
    const int bz  = blockIdx.y;

    float wl[11];
#pragma unroll
    for (int t = 0; t < 11; ++t) wl[t] = w11[t];

    const h2* F0 = (const h2*)(fields + (size_t)bz * 10 * VOL);
    const h2* F1 = F0 + (size_t)VOL;
    const _Float16* F2 = (const _Float16*)(F1 + (size_t)VOL);

    float bX[11], bY[11], bXX[11], bYY[11], bXY[11];
#pragma unroll
    for (int t = 0; t < 11; ++t) { bX[t] = 0; bY[t] = 0; bXX[t] = 0; bYY[t] = 0; bXY[t] = 0; }

    float acc = 0.f;
#pragma unroll
    for (int s = 0; s < 42; ++s) {
        const int dd = DHALF * 32 - 5 + s;          // compile-time after unroll
        const int slot = s % 11;                    // compile-time
        if (dd >= 0 && dd < 64) {                   // compile-time
            size_t idx = (size_t)dd * HW + col;
            h2 v0 = F0[idx];
            h2 v1 = F1[idx];
            _Float16 vxy = F2[idx];
            bX[slot]  = (float)v0[0];
            bY[slot]  = (float)v0[1];
            bXX[slot] = (float)v1[0];
            bYY[slot] = (float)v1[1];
            bXY[slot] = (float)vxy;
        } else {
            bX[slot] = 0; bY[slot] = 0; bXX[slot] = 0; bYY[slot] = 0; bXY[slot] = 0;
        }

        if (s >= 10) {                              // compile-time; emit depth DHALF*32 + s-10
            float mX = 0, mY = 0, cXX = 0, cYY = 0, cXY = 0;
#pragma unroll
            for (int t = 0; t < 11; ++t) {
                const int j = (s + 1 + t) % 11;     // compile-time
                float wt = wl[t];
                mX  += wt * bX[j];
                mY  += wt * bY[j];
                cXX += wt * bXX[j];
                cYY += wt * bYY[j];
                cXY += wt * bXY[j];
            }
            float mx2 = mX * mX, my2 = mY * mY, mxy = mX * mY;
            float sx2 = cXX - mx2, sy2 = cYY - my2, sxy = cXY - mxy;
            float num = (2.f * mxy + C1v) * (2.f * sxy + C2v);
            float den = (mx2 + my2 + C1v) * (sx2 + sy2 + C2v);
            acc += num * __builtin_amdgcn_rcpf(den + EPSv);
        }
    }

    // reduce 256 threads -> one partial per block (deterministic)
    for (int off = 32; off; off >>= 1) acc += __shfl_down(acc, off, 64);
    __shared__ float wsum[4];
    int lane = threadIdx.x & 63, wid = threadIdx.x >> 6;
    if (lane == 0) wsum[wid] = acc;
    __syncthreads();
    if (threadIdx.x == 0) {
        float s = wsum[0] + wsum[1] + wsum[2] + wsum[3];
        partials[(size_t)(b0 + bz) * 512 + DHALF * 256 + blockIdx.x] = (double)s;
    }
}

__global__ void finalize(const double* __restrict__ partials, float* __restrict__ out, int n) {
    __shared__ double sh[256];
    double s = 0.0;
    for (int i = threadIdx.x; i < n; i += 256) s += partials[i];
    sh[threadIdx.x] = s;
    __syncthreads();
    for (int stride = 128; stride; stride >>= 1) {
        if (threadIdx.x < stride) sh[threadIdx.x] += sh[threadIdx.x + stride];
        __syncthreads();
    }
    if (threadIdx.x == 0) out[0] = 1.0f - (float)(sh[0] / (double)NTOT);
}

extern "C" void kernel_launch(void* const* d_in, const int* in_sizes, int n_in,
                              void* d_out, int out_size, void* d_ws, size_t ws_size,
                              hipStream_t stream) {
    const float* x  = (const float*)d_in[0];
    const float* y  = (const float*)d_in[1];
    const float* k3 = (const float*)d_in[2];
    float* out = (float*)d_out;

    char* ws = (char*)d_ws;
    float*   w11      = (float*)ws;
    double*  partials = (double*)(ws + 64);
    char*    fields   = ws + 16640;

    const size_t perBatch = (size_t)10 * VOL;   // packed fp16 fields per batch (bytes)
    const bool all4 = ws_size >= 16640 + 4 * perBatch;

    init_weights<<<1, 64, 0, stream>>>(k3, w11);

    if (all4) {
        blur_hw      <<<dim3(4, 16, 256), 256, 0, stream>>>(x, y, w11, fields, 0);
        dconv_ssim<0><<<dim3(256, 4),     256, 0, stream>>>(fields, w11, partials, 0);
        dconv_ssim<1><<<dim3(256, 4),     256, 0, stream>>>(fields, w11, partials, 0);
    } else {
        for (int b = 0; b < 4; ++b) {
            blur_hw      <<<dim3(4, 16, 64), 256, 0, stream>>>(x, y, w11, fields, b);
            dconv_ssim<0><<<dim3(256, 1),    256, 0, stream>>>(fields, w11, partials, b);
            dconv_ssim<1><<<dim3(256, 1),    256, 0, stream>>>(fields, w11, partials, b);
        }
    }

    finalize<<<1, 256, 0, stream>>>(partials, out, 2048);
}

// Round 7
// 204.809 us; speedup vs baseline: 1.2544x; 1.2544x over previous
//
#include <hip/hip_runtime.h>

#define HW   (256*256)        // 65536
#define VOL  (64*HW)          // 4194304 per batch volume
#define NTOT (4ull*VOL)
#define C1v  1e-4f
#define C2v  9e-4f
#define EPSv 1e-8f

typedef float    f2 __attribute__((ext_vector_type(2)));
typedef _Float16 h2 __attribute__((ext_vector_type(2)));
typedef _Float16 h4 __attribute__((ext_vector_type(4)));

// ws layout:
// [0      .. 63]     : w[11] float (1D separable weights)
// [64     .. 16447]  : partials[2048] double
// [16640  .. ]       : packed field volumes, 10 bytes/element per batch:
//                      F0 = h2{X,Y}[VOL], F1 = h2{XX,YY}[VOL], F2 = f16 XY[VOL]

__global__ void init_weights(const float* __restrict__ k3, float* __restrict__ w) {
    int i = threadIdx.x;
    if (i < 11) {
        float s = 0.f;
        for (int t = 0; t < 121; ++t) s += k3[i * 121 + t];
        w[i] = s;   // k3 is separable: row-sum = 1D weight
    }
}

// Pass 1 (round-5 structure, packed stores): f2 staging + fp32 W-conv + fp16 tf
// + packed-h2 H-conv.  grid: (4, 16, 64*nb) x 256.  Tile = 16(h) x 64(w).
__global__ __launch_bounds__(256) void blur_hw(
    const float* __restrict__ x, const float* __restrict__ y,
    const float* __restrict__ w11, char* __restrict__ fields, int b0)
{
    __shared__ f2 sxy[26][74];            // 15,392 B
    __shared__ _Float16 tf[5][26][64];    // 16,640 B  -> 32,032 B total

    const int d   = blockIdx.z & 63;
    const int bz  = blockIdx.z >> 6;
    const int h0  = blockIdx.y * 16;
    const int w0  = blockIdx.x * 64;
    const int tid = threadIdx.x;

    float wl[11];
#pragma unroll
    for (int t = 0; t < 11; ++t) wl[t] = w11[t];

    const float* xb = x + (size_t)(b0 + bz) * VOL + (size_t)d * HW;
    const float* yb = y + (size_t)(b0 + bz) * VOL + (size_t)d * HW;

    for (int p = tid; p < 26 * 74; p += 256) {
        int r = p / 74, c = p - r * 74;
        int gh = h0 - 5 + r, gw = w0 - 5 + c;
        f2 v = {0.f, 0.f};
        if ((unsigned)gh < 256u && (unsigned)gw < 256u) {
            v.x = xb[gh * 256 + gw];
            v.y = yb[gh * 256 + gw];
        }
        sxy[r][c] = v;
    }
    __syncthreads();

    for (int p = tid; p < 26 * 64; p += 256) {
        int r = p >> 6, c = p & 63;
        float aX = 0, aY = 0, aXX = 0, aYY = 0, aXY = 0;
#pragma unroll
        for (int k = 0; k < 11; ++k) {
            f2 v = sxy[r][c + k];
            float wk = wl[k];
            aX  += wk * v.x;
            aY  += wk * v.y;
            aXX += wk * (v.x * v.x);
            aYY += wk * (v.y * v.y);
            aXY += wk * (v.x * v.y);
        }
        tf[0][r][c] = (_Float16)aX;
        tf[1][r][c] = (_Float16)aY;
        tf[2][r][c] = (_Float16)aXX;
        tf[3][r][c] = (_Float16)aYY;
        tf[4][r][c] = (_Float16)aXY;
    }
    __syncthreads();

    h2 wl2[11];
#pragma unroll
    for (int t = 0; t < 11; ++t) { _Float16 h = (_Float16)wl[t]; wl2[t] = (h2){h, h}; }

    h2* F0 = (h2*)(fields + (size_t)bz * 10 * VOL);
    h2* F1 = F0 + (size_t)VOL;
    _Float16* F2 = (_Float16*)(F1 + (size_t)VOL);

#pragma unroll
    for (int i = 0; i < 2; ++i) {
        int p = tid + i * 256;
        int r = p >> 5, c2 = p & 31;       // thread owns columns (2c2, 2c2+1) of row r
        h2 o0 = {0,0}, o1 = {0,0}, o2 = {0,0}, o3 = {0,0}, o4 = {0,0};
#pragma unroll
        for (int j = 0; j < 11; ++j) {
            h2 w2 = wl2[j];
            o0 += w2 * *(const h2*)&tf[0][r + j][2 * c2];
            o1 += w2 * *(const h2*)&tf[1][r + j][2 * c2];
            o2 += w2 * *(const h2*)&tf[2][r + j][2 * c2];
            o3 += w2 * *(const h2*)&tf[3][r + j][2 * c2];
            o4 += w2 * *(const h2*)&tf[4][r + j][2 * c2];
        }
        // repack per-field column pairs -> per-element packed layout
        size_t oi = (size_t)d * HW + (size_t)(h0 + r) * 256 + (w0 + 2 * c2);
        *(h4*)&F0[oi] = (h4){o0[0], o1[0], o0[1], o1[1]};   // {X,Y} x2
        *(h4*)&F1[oi] = (h4){o2[0], o3[0], o2[1], o3[1]};   // {XX,YY} x2
        *(h2*)&F2[oi] = o4;                                  // XY x2
    }
}

// Pass 2: D-conv via scalar fp32 register rings, packed field loads.
// DHALF compile-time so ALL guards fold; grid: (256, nb) x 256.
template<int DHALF>
__global__ __launch_bounds__(256) void dconv_ssim(
    const char* __restrict__ fields, const float* __restrict__ w11,
    double* __restrict__ partials, int b0)
{
    const int col = blockIdx.x * 256 + threadIdx.x;  // 0..65535 within slice
    const int bz  = blockIdx.y;

    float wl[11];
#pragma unroll
    for (int t = 0; t < 11; ++t) wl[t] = w11[t];

    const h2* F0 = (const h2*)(fields + (size_t)bz * 10 * VOL);
    const h2* F1 = F0 + (size_t)VOL;
    const _Float16* F2 = (const _Float16*)(F1 + (size_t)VOL);

    float bX[11], bY[11], bXX[11], bYY[11], bXY[11];
#pragma unroll
    for (int t = 0; t < 11; ++t) { bX[t] = 0; bY[t] = 0; bXX[t] = 0; bYY[t] = 0; bXY[t] = 0; }

    float acc = 0.f;
#pragma unroll
    for (int s = 0; s < 42; ++s) {
        const int dd = DHALF * 32 - 5 + s;          // compile-time after unroll
        const int slot = s % 11;                    // compile-time
        if (dd >= 0 && dd < 64) {                   // compile-time
            size_t idx = (size_t)dd * HW + col;
            h2 v0 = F0[idx];
            h2 v1 = F1[idx];
            _Float16 vxy = F2[idx];
            bX[slot]  = (float)v0[0];
            bY[slot]  = (float)v0[1];
            bXX[slot] = (float)v1[0];
            bYY[slot] = (float)v1[1];
            bXY[slot] = (float)vxy;
        } else {
            bX[slot] = 0; bY[slot] = 0; bXX[slot] = 0; bYY[slot] = 0; bXY[slot] = 0;
        }

        if (s >= 10) {                              // compile-time; emit depth DHALF*32 + s-10
            float mX = 0, mY = 0, cXX = 0, cYY = 0, cXY = 0;
#pragma unroll
            for (int t = 0; t < 11; ++t) {
                const int j = (s + 1 + t) % 11;     // compile-time
                float wt = wl[t];
                mX  += wt * bX[j];
                mY  += wt * bY[j];
                cXX += wt * bXX[j];
                cYY += wt * bYY[j];
                cXY += wt * bXY[j];
            }
            float mx2 = mX * mX, my2 = mY * mY, mxy = mX * mY;
            float sx2 = cXX - mx2, sy2 = cYY - my2, sxy = cXY - mxy;
            float num = (2.f * mxy + C1v) * (2.f * sxy + C2v);
            float den = (mx2 + my2 + C1v) * (sx2 + sy2 + C2v);
            acc += num * __builtin_amdgcn_rcpf(den + EPSv);
        }
    }

    // reduce 256 threads -> one partial per block (deterministic)
    for (int off = 32; off; off >>= 1) acc += __shfl_down(acc, off, 64);
    __shared__ float wsum[4];
    int lane = threadIdx.x & 63, wid = threadIdx.x >> 6;
    if (lane == 0) wsum[wid] = acc;
    __syncthreads();
    if (threadIdx.x == 0) {
        float s = wsum[0] + wsum[1] + wsum[2] + wsum[3];
        partials[(size_t)(b0 + bz) * 512 + DHALF * 256 + blockIdx.x] = (double)s;
    }
}

__global__ void finalize(const double* __restrict__ partials, float* __restrict__ out, int n) {
    __shared__ double sh[256];
    double s = 0.0;
    for (int i = threadIdx.x; i < n; i += 256) s += partials[i];
    sh[threadIdx.x] = s;
    __syncthreads();
    for (int stride = 128; stride; stride >>= 1) {
        if (threadIdx.x < stride) sh[threadIdx.x] += sh[threadIdx.x + stride];
        __syncthreads();
    }
    if (threadIdx.x == 0) out[0] = 1.0f - (float)(sh[0] / (double)NTOT);
}

extern "C" void kernel_launch(void* const* d_in, const int* in_sizes, int n_in,
                              void* d_out, int out_size, void* d_ws, size_t ws_size,
                              hipStream_t stream) {
    const float* x  = (const float*)d_in[0];
    const float* y  = (const float*)d_in[1];
    const float* k3 = (const float*)d_in[2];
    float* out = (float*)d_out;

    char* ws = (char*)d_ws;
    float*   w11      = (float*)ws;
    double*  partials = (double*)(ws + 64);
    char*    fields   = ws + 16640;

    const size_t perBatch = (size_t)10 * VOL;   // packed fp16 fields per batch (bytes)
    const bool all4 = ws_size >= 16640 + 4 * perBatch;

    init_weights<<<1, 64, 0, stream>>>(k3, w11);

    if (all4) {
        blur_hw      <<<dim3(4, 16, 256), 256, 0, stream>>>(x, y, w11, fields, 0);
        dconv_ssim<0><<<dim3(256, 4),     256, 0, stream>>>(fields, w11, partials, 0);
        dconv_ssim<1><<<dim3(256, 4),     256, 0, stream>>>(fields, w11, partials, 0);
    } else {
        for (int b = 0; b < 4; ++b) {
            blur_hw      <<<dim3(4, 16, 64), 256, 0, stream>>>(x, y, w11, fields, b);
            dconv_ssim<0><<<dim3(256, 1),    256, 0, stream>>>(fields, w11, partials, b);
            dconv_ssim<1><<<dim3(256, 1),    256, 0, stream>>>(fields, w11, partials, b);
        }
    }

    finalize<<<1, 256, 0, stream>>>(partials, out, 2048);
}

// Round 8
// 174.274 us; speedup vs baseline: 1.4742x; 1.1752x over previous
//
#include <hip/hip_runtime.h>

#define HW   (256*256)        // 65536
#define VOL  (64*HW)          // 4194304 per batch volume
#define NTOT (4ull*VOL)
#define C1v  1e-4f
#define C2v  9e-4f
#define EPSv 1e-8f

typedef float    f2 __attribute__((ext_vector_type(2)));
typedef _Float16 h2 __attribute__((ext_vector_type(2)));
typedef _Float16 h4 __attribute__((ext_vector_type(4)));
typedef _Float16 h8 __attribute__((ext_vector_type(8)));

// ws layout:
// [0      .. 63]     : w[11] float (1D separable weights)
// [64     .. 16447]  : partials[2048] double
// [16640  .. ]       : packed field volumes, 10 bytes/element per batch:
//                      F0 = h2{X,Y}[VOL], F1 = h2{XX,YY}[VOL], F2 = f16 XY[VOL]

__global__ void init_weights(const float* __restrict__ k3, float* __restrict__ w) {
    int i = threadIdx.x;
    if (i < 11) {
        float s = 0.f;
        for (int t = 0; t < 121; ++t) s += k3[i * 121 + t];
        w[i] = s;   // k3 is separable: row-sum = 1D weight
    }
}

// Pass 1, full fp16 pipeline:
//  stage {x,y} h2 -> W-conv (4-col register blocks, pk_fma) -> TA/TB interleaved
//  -> H-conv (b128 tap-pair reads, pk_fma) -> packed field stores.
// grid: (4, 16, 64*nb) x 256.  Tile = 16(h) x 64(w) of one d-slice.
__global__ __launch_bounds__(256) void blur_hw(
    const float* __restrict__ x, const float* __restrict__ y,
    const float* __restrict__ w11, char* __restrict__ fields, int b0)
{
    __shared__ alignas(16) h2 S[26][76];         // {x,y}        7,904 B
    __shared__ alignas(16) h4 TA[26][64];        // {X,Y,XX,YY} 13,312 B
    __shared__ alignas(16) _Float16 TB[26][64];  // XY           3,328 B  -> 24,544 B

    const int d   = blockIdx.z & 63;
    const int bz  = blockIdx.z >> 6;
    const int h0  = blockIdx.y * 16;
    const int w0  = blockIdx.x * 64;
    const int tid = threadIdx.x;

    h2 w2[11];
    _Float16 wh[11];
#pragma unroll
    for (int t = 0; t < 11; ++t) {
        _Float16 h = (_Float16)w11[t];
        wh[t] = h;
        w2[t] = (h2){h, h};
    }

    const float* xb = x + (size_t)(b0 + bz) * VOL + (size_t)d * HW;
    const float* yb = y + (size_t)(b0 + bz) * VOL + (size_t)d * HW;

    // stage halo tile 26 x 74 as fp16 {x,y}
    for (int p = tid; p < 26 * 74; p += 256) {
        int r = p / 74, c = p - r * 74;
        int gh = h0 - 5 + r, gw = w0 - 5 + c;
        float xv = 0.f, yv = 0.f;
        if ((unsigned)gh < 256u && (unsigned)gw < 256u) {
            xv = xb[gh * 256 + gw];
            yv = yb[gh * 256 + gw];
        }
        S[r][c] = (h2){(_Float16)xv, (_Float16)yv};
    }
    __syncthreads();

    // W-conv: 26 rows x 16 col-groups (4 cols each) = 416 items
#pragma unroll
    for (int it = 0; it < 2; ++it) {
        int item = tid + it * 256;
        if (item < 416) {
            int r = item >> 4, c0 = (item & 15) * 4;
            // window of 14 values, read as 7 x b64
            h2 vxy[14], vsq[14];
            _Float16 vp[14];
#pragma unroll
            for (int i = 0; i < 7; ++i) {
                h4 rawp = *(const h4*)&S[r][c0 + 2 * i];
                h2 lo = (h2){rawp[0], rawp[1]};
                h2 hi = (h2){rawp[2], rawp[3]};
                vxy[2*i]   = lo;        vxy[2*i+1] = hi;
                vsq[2*i]   = lo * lo;   vsq[2*i+1] = hi * hi;
                vp[2*i]    = lo[0] * lo[1];
                vp[2*i+1]  = hi[0] * hi[1];
            }
            h2 aXY[4], aSQ[4];
            _Float16 aP[4];
#pragma unroll
            for (int p = 0; p < 4; ++p) { aXY[p] = (h2){0,0}; aSQ[p] = (h2){0,0}; aP[p] = (_Float16)0; }
#pragma unroll
            for (int k = 0; k < 11; ++k) {
#pragma unroll
                for (int p = 0; p < 4; ++p) {
                    aXY[p] += w2[k] * vxy[p + k];
                    aSQ[p] += w2[k] * vsq[p + k];
                    aP[p]  += wh[k] * vp[p + k];
                }
            }
#pragma unroll
            for (int p = 0; p < 4; ++p) {
                TA[r][c0 + p] = (h4){aXY[p][0], aXY[p][1], aSQ[p][0], aSQ[p][1]};
                TB[r][c0 + p] = aP[p];
            }
        }
    }
    __syncthreads();

    h2* F0 = (h2*)(fields + (size_t)bz * 10 * VOL);
    h2* F1 = F0 + (size_t)VOL;
    _Float16* F2 = (_Float16*)(F1 + (size_t)VOL);

    // H-conv: 512 output pairs, 2 per thread; b128 + b32 reads per tap
#pragma unroll
    for (int it = 0; it < 2; ++it) {
        int pi = tid + it * 256;
        int r = pi >> 5, c = (pi & 31) * 2;
        h2 A_lo = {0,0}, A_hi = {0,0}, S_lo = {0,0}, S_hi = {0,0}, P2 = {0,0};
#pragma unroll
        for (int j = 0; j < 11; ++j) {
            h8 t = *(const h8*)&TA[r + j][c];      // 16B aligned (c even)
            h2 xyp = *(const h2*)&TB[r + j][c];    // 4B aligned
            h2 w = w2[j];
            A_lo += w * (h2){t[0], t[1]};
            S_lo += w * (h2){t[2], t[3]};
            A_hi += w * (h2){t[4], t[5]};
            S_hi += w * (h2){t[6], t[7]};
            P2   += w * xyp;
        }
        size_t oi = (size_t)d * HW + (size_t)(h0 + r) * 256 + (w0 + c);
        *(h4*)&F0[oi] = (h4){A_lo[0], A_lo[1], A_hi[0], A_hi[1]};
        *(h4*)&F1[oi] = (h4){S_lo[0], S_lo[1], S_hi[0], S_hi[1]};
        *(h2*)&F2[oi] = P2;
    }
}

// Pass 2: D-conv via scalar fp32 register rings, packed field loads.
// DHALF compile-time so ALL guards fold; grid: (256, nb) x 256.
template<int DHALF>
__global__ __launch_bounds__(256) void dconv_ssim(
    const char* __restrict__ fields, const float* __restrict__ w11,
    double* __restrict__ partials, int b0)
{
    const int col = blockIdx.x * 256 + threadIdx.x;  // 0..65535 within slice
    const int bz  = blockIdx.y;

    float wl[11];
#pragma unroll
    for (int t = 0; t < 11; ++t) wl[t] = w11[t];

    const h2* F0 = (const h2*)(fields + (size_t)bz * 10 * VOL);
    const h2* F1 = F0 + (size_t)VOL;
    const _Float16* F2 = (const _Float16*)(F1 + (size_t)VOL);

    float bX[11], bY[11], bXX[11], bYY[11], bXY[11];
#pragma unroll
    for (int t = 0; t < 11; ++t) { bX[t] = 0; bY[t] = 0; bXX[t] = 0; bYY[t] = 0; bXY[t] = 0; }

    float acc = 0.f;
#pragma unroll
    for (int s = 0; s < 42; ++s) {
        const int dd = DHALF * 32 - 5 + s;          // compile-time after unroll
        const int slot = s % 11;                    // compile-time
        if (dd >= 0 && dd < 64) {                   // compile-time
            size_t idx = (size_t)dd * HW + col;
            h2 v0 = F0[idx];
            h2 v1 = F1[idx];
            _Float16 vxy = F2[idx];
            bX[slot]  = (float)v0[0];
            bY[slot]  = (float)v0[1];
            bXX[slot] = (float)v1[0];
            bYY[slot] = (float)v1[1];
            bXY[slot] = (float)vxy;
        } else {
            bX[slot] = 0; bY[slot] = 0; bXX[slot] = 0; bYY[slot] = 0; bXY[slot] = 0;
        }

        if (s >= 10) {                              // compile-time; emit depth DHALF*32 + s-10
            float mX = 0, mY = 0, cXX = 0, cYY = 0, cXY = 0;
#pragma unroll
            for (int t = 0; t < 11; ++t) {
                const int j = (s + 1 + t) % 11;     // compile-time
                float wt = wl[t];
                mX  += wt * bX[j];
                mY  += wt * bY[j];
                cXX += wt * bXX[j];
                cYY += wt * bYY[j];
                cXY += wt * bXY[j];
            }
            float mx2 = mX * mX, my2 = mY * mY, mxy = mX * mY;
            float sx2 = cXX - mx2, sy2 = cYY - my2, sxy = cXY - mxy;
            float num = (2.f * mxy + C1v) * (2.f * sxy + C2v);
            float den = (mx2 + my2 + C1v) * (sx2 + sy2 + C2v);
            acc += num * __builtin_amdgcn_rcpf(den + EPSv);
        }
    }

    // reduce 256 threads -> one partial per block (deterministic)
    for (int off = 32; off; off >>= 1) acc += __shfl_down(acc, off, 64);
    __shared__ float wsum[4];
    int lane = threadIdx.x & 63, wid = threadIdx.x >> 6;
    if (lane == 0) wsum[wid] = acc;
    __syncthreads();
    if (threadIdx.x == 0) {
        float s = wsum[0] + wsum[1] + wsum[2] + wsum[3];
        partials[(size_t)(b0 + bz) * 512 + DHALF * 256 + blockIdx.x] = (double)s;
    }
}

__global__ void finalize(const double* __restrict__ partials, float* __restrict__ out, int n) {
    __shared__ double sh[256];
    double s = 0.0;
    for (int i = threadIdx.x; i < n; i += 256) s += partials[i];
    sh[threadIdx.x] = s;
    __syncthreads();
    for (int stride = 128; stride; stride >>= 1) {
        if (threadIdx.x < stride) sh[threadIdx.x] += sh[threadIdx.x + stride];
        __syncthreads();
    }
    if (threadIdx.x == 0) out[0] = 1.0f - (float)(sh[0] / (double)NTOT);
}

extern "C" void kernel_launch(void* const* d_in, const int* in_sizes, int n_in,
                              void* d_out, int out_size, void* d_ws, size_t ws_size,
                              hipStream_t stream) {
    const float* x  = (const float*)d_in[0];
    const float* y  = (const float*)d_in[1];
    const float* k3 = (const float*)d_in[2];
    float* out = (float*)d_out;

    char* ws = (char*)d_ws;
    float*   w11      = (float*)ws;
    double*  partials = (double*)(ws + 64);
    char*    fields   = ws + 16640;

    const size_t perBatch = (size_t)10 * VOL;   // packed fp16 fields per batch (bytes)
    const bool all4 = ws_size >= 16640 + 4 * perBatch;

    init_weights<<<1, 64, 0, stream>>>(k3, w11);

    if (all4) {
        blur_hw      <<<dim3(4, 16, 256), 256, 0, stream>>>(x, y, w11, fields, 0);
        dconv_ssim<0><<<dim3(256, 4),     256, 0, stream>>>(fields, w11, partials, 0);
        dconv_ssim<1><<<dim3(256, 4),     256, 0, stream>>>(fields, w11, partials, 0);
    } else {
        for (int b = 0; b < 4; ++b) {
            blur_hw      <<<dim3(4, 16, 64), 256, 0, stream>>>(x, y, w11, fields, b);
            dconv_ssim<0><<<dim3(256, 1),    256, 0, stream>>>(fields, w11, partials, b);
            dconv_ssim<1><<<dim3(256, 1),    256, 0, stream>>>(fields, w11, partials, b);
        }
    }

    finalize<<<1, 256, 0, stream>>>(partials, out, 2048);
}

// Round 9
// 155.080 us; speedup vs baseline: 1.6567x; 1.1238x over previous
//
#include <hip/hip_runtime.h>

#define HW   (256*256)        // 65536
#define VOL  (64*HW)          // 4194304 per batch volume
#define NTOT (4ull*VOL)
#define C1v  1e-4f
#define C2v  9e-4f
#define EPSv 1e-8f

typedef float    f2 __attribute__((ext_vector_type(2)));
typedef float    f4 __attribute__((ext_vector_type(4)));
typedef _Float16 h2 __attribute__((ext_vector_type(2)));
typedef _Float16 h4 __attribute__((ext_vector_type(4)));
typedef _Float16 h8 __attribute__((ext_vector_type(8)));

// ws layout:
// [0      .. 63]     : w[11] float (1D separable weights)
// [64     .. 16447]  : partials[2048] double
// [16640  .. ]       : packed field volumes, 10 bytes/element per batch:
//                      F0 = h2{X,Y}[VOL], F1 = h2{XX,YY}[VOL], F2 = f16 XY[VOL]

__global__ void init_weights(const float* __restrict__ k3, float* __restrict__ w) {
    int i = threadIdx.x;
    if (i < 11) {
        float s = 0.f;
        for (int t = 0; t < 121; ++t) s += k3[i * 121 + t];
        w[i] = s;   // k3 is separable: row-sum = 1D weight
    }
}

// Pass 1 via MFMA banded matmuls.
// Per block: 16(h) x 64(w) output tile of one d-slice.
//  stage: 5 product arrays P[f][32][80] fp16 (halo rows/cols zero-padded;
//         staged col c <-> gw = w0-6+c so col-pairs are even-aligned float2 loads)
//  W-conv: D = A(data 16/32rows x K32) * B(band K32 x N16), band WB[n][k]=wt[k-n-1]
//          -> Tt[f][col64][row32] fp16 (transposed, zero rows 26..31)
//  H-conv: D = A(band M16 x K32, AH[m][k]=wt[k-m]) * B(Tt cols)
//          -> packed global stores F0/F1/F2.
// grid: (4, 16, 64*nb) x 256.
__global__ __launch_bounds__(256) void blur_hw(
    const float* __restrict__ x, const float* __restrict__ y,
    const float* __restrict__ w11, char* __restrict__ fields, int b0)
{
    __shared__ alignas(16) _Float16 P[5][32][80];   // 25,600 B
    __shared__ alignas(16) _Float16 Tt[5][64][32];  // 20,480 B
    __shared__ alignas(16) _Float16 WB[16][32];     //  1,024 B
    __shared__ alignas(16) _Float16 AH[16][32];     //  1,024 B  -> 48,128 B

    const int d   = blockIdx.z & 63;
    const int bz  = blockIdx.z >> 6;
    const int h0  = blockIdx.y * 16;
    const int w0  = blockIdx.x * 64;
    const int tid = threadIdx.x;

    const float* xb = x + (size_t)(b0 + bz) * VOL + (size_t)d * HW;
    const float* yb = y + (size_t)(b0 + bz) * VOL + (size_t)d * HW;

    // ---- build band tables (512 = 2*256, exact) ----
#pragma unroll
    for (int it = 0; it < 2; ++it) {
        int t = tid + it * 256;
        int n = t >> 5, k = t & 31;
        int i1 = k - n - 1;                 // W band (staged-col shift +1)
        int i2 = k - n;                     // H band
        int c1 = min(max(i1, 0), 10);
        int c2 = min(max(i2, 0), 10);
        float v1 = ((unsigned)i1 <= 10u) ? w11[c1] : 0.f;
        float v2 = ((unsigned)i2 <= 10u) ? w11[c2] : 0.f;
        WB[n][k] = (_Float16)v1;
        AH[n][k] = (_Float16)v2;
    }

    // ---- stage products: 32 rows x 40 col-pairs = 1280 = 5*256, exact ----
#pragma unroll
    for (int it = 0; it < 5; ++it) {
        int p = tid + it * 256;
        int r = p / 40;
        int j = p - r * 40;
        int gh = h0 - 5 + r;
        int gw = w0 - 6 + 2 * j;            // even
        bool ok = (r < 26) && ((unsigned)gh < 256u) && ((unsigned)gw < 256u);
        int ghc = min(max(gh, 0), 255);
        int gwc = min(max(gw, 0), 254);     // even-safe clamp
        int idx = ghc * 256 + gwc;
        f2 xv = *(const f2*)&xb[idx];
        f2 yv = *(const f2*)&yb[idx];
        if (!ok) { xv = (f2){0.f, 0.f}; yv = (f2){0.f, 0.f}; }
        float xx0 = xv[0] * xv[0], xx1 = xv[1] * xv[1];
        float yy0 = yv[0] * yv[0], yy1 = yv[1] * yv[1];
        float xy0 = xv[0] * yv[0], xy1 = xv[1] * yv[1];
        char* pb = (char*)P + r * 160 + j * 4;
        *(h2*)(pb + 0)     = (h2){(_Float16)xv[0], (_Float16)xv[1]};
        *(h2*)(pb + 5120)  = (h2){(_Float16)yv[0], (_Float16)yv[1]};
        *(h2*)(pb + 10240) = (h2){(_Float16)xx0, (_Float16)xx1};
        *(h2*)(pb + 15360) = (h2){(_Float16)yy0, (_Float16)yy1};
        *(h2*)(pb + 20480) = (h2){(_Float16)xy0, (_Float16)xy1};
    }
    __syncthreads();

    const int lane = tid & 63, wid = tid >> 6;
    const int lm = lane & 15, lk = lane >> 4;

    // ---- W-conv: wave = N-chunk; 5 fields x 2 M-chunks per wave ----
    {
        h8 bw = *(const h8*)((const char*)WB + lm * 64 + lk * 16);
        const char* Ab = (const char*)P + lm * 160 + wid * 32 + lk * 16;
        char* Tb = (char*)Tt + (wid * 16 + lm) * 64 + lk * 8;
#pragma unroll
        for (int f = 0; f < 5; ++f) {
#pragma unroll
            for (int mc = 0; mc < 2; ++mc) {
                h8 a = *(const h8*)(Ab + f * 5120 + mc * 2560);
                f4 dv = __builtin_amdgcn_mfma_f32_16x16x32_f16(
                            a, bw, (f4){0.f, 0.f, 0.f, 0.f}, 0, 0, 0);
                h4 pk = (h4){(_Float16)dv[0], (_Float16)dv[1],
                             (_Float16)dv[2], (_Float16)dv[3]};
                *(h4*)(Tb + f * 4096 + mc * 32) = pk;
            }
        }
    }
    __syncthreads();

    // ---- H-conv: wave = N-chunk; 5 fields, then packed stores ----
    {
        h8 ah = *(const h8*)((const char*)AH + lm * 64 + lk * 16);
        const char* Tb = (const char*)Tt + (wid * 16 + lm) * 64 + lk * 16;
        f4 d0, d1, d2, d3, d4;
        d0 = __builtin_amdgcn_mfma_f32_16x16x32_f16(ah, *(const h8*)(Tb + 0),
                 (f4){0.f,0.f,0.f,0.f}, 0, 0, 0);
        d1 = __builtin_amdgcn_mfma_f32_16x16x32_f16(ah, *(const h8*)(Tb + 4096),
                 (f4){0.f,0.f,0.f,0.f}, 0, 0, 0);
        d2 = __builtin_amdgcn_mfma_f32_16x16x32_f16(ah, *(const h8*)(Tb + 8192),
                 (f4){0.f,0.f,0.f,0.f}, 0, 0, 0);
        d3 = __builtin_amdgcn_mfma_f32_16x16x32_f16(ah, *(const h8*)(Tb + 12288),
                 (f4){0.f,0.f,0.f,0.f}, 0, 0, 0);
        d4 = __builtin_amdgcn_mfma_f32_16x16x32_f16(ah, *(const h8*)(Tb + 16384),
                 (f4){0.f,0.f,0.f,0.f}, 0, 0, 0);

        h2* F0 = (h2*)(fields + (size_t)bz * 10 * VOL);
        h2* F1 = F0 + (size_t)VOL;
        _Float16* F2 = (_Float16*)(F1 + (size_t)VOL);

        const int col = w0 + wid * 16 + lm;
#pragma unroll
        for (int rg = 0; rg < 4; ++rg) {
            int row = lk * 4 + rg;
            size_t oi = (size_t)d * HW + (size_t)(h0 + row) * 256 + col;
            F0[oi] = (h2){(_Float16)d0[rg], (_Float16)d1[rg]};
            F1[oi] = (h2){(_Float16)d2[rg], (_Float16)d3[rg]};
            F2[oi] = (_Float16)d4[rg];
        }
    }
}

// Pass 2: D-conv via scalar fp32 register rings, packed field loads.
// DHALF compile-time so ALL guards fold; grid: (256, nb) x 256.
template<int DHALF>
__global__ __launch_bounds__(256) void dconv_ssim(
    const char* __restrict__ fields, const float* __restrict__ w11,
    double* __restrict__ partials, int b0)
{
    const int col = blockIdx.x * 256 + threadIdx.x;  // 0..65535 within slice
    const int bz  = blockIdx.y;

    float wl[11];
#pragma unroll
    for (int t = 0; t < 11; ++t) wl[t] = w11[t];

    const h2* F0 = (const h2*)(fields + (size_t)bz * 10 * VOL);
    const h2* F1 = F0 + (size_t)VOL;
    const _Float16* F2 = (const _Float16*)(F1 + (size_t)VOL);

    float bX[11], bY[11], bXX[11], bYY[11], bXY[11];
#pragma unroll
    for (int t = 0; t < 11; ++t) { bX[t] = 0; bY[t] = 0; bXX[t] = 0; bYY[t] = 0; bXY[t] = 0; }

    float acc = 0.f;
#pragma unroll
    for (int s = 0; s < 42; ++s) {
        const int dd = DHALF * 32 - 5 + s;          // compile-time after unroll
        const int slot = s % 11;                    // compile-time
        if (dd >= 0 && dd < 64) {                   // compile-time
            size_t idx = (size_t)dd * HW + col;
            h2 v0 = F0[idx];
            h2 v1 = F1[idx];
            _Float16 vxy = F2[idx];
            bX[slot]  = (float)v0[0];
            bY[slot]  = (float)v0[1];
            bXX[slot] = (float)v1[0];
            bYY[slot] = (float)v1[1];
            bXY[slot] = (float)vxy;
        } else {
            bX[slot] = 0; bY[slot] = 0; bXX[slot] = 0; bYY[slot] = 0; bXY[slot] = 0;
        }

        if (s >= 10) {                              // compile-time; emit depth DHALF*32 + s-10
            float mX = 0, mY = 0, cXX = 0, cYY = 0, cXY = 0;
#pragma unroll
            for (int t = 0; t < 11; ++t) {
                const int j = (s + 1 + t) % 11;     // compile-time
                float wt = wl[t];
                mX  += wt * bX[j];
                mY  += wt * bY[j];
                cXX += wt * bXX[j];
                cYY += wt * bYY[j];
                cXY += wt * bXY[j];
            }
            float mx2 = mX * mX, my2 = mY * mY, mxy = mX * mY;
            float sx2 = cXX - mx2, sy2 = cYY - my2, sxy = cXY - mxy;
            float num = (2.f * mxy + C1v) * (2.f * sxy + C2v);
            float den = (mx2 + my2 + C1v) * (sx2 + sy2 + C2v);
            acc += num * __builtin_amdgcn_rcpf(den + EPSv);
        }
    }

    // reduce 256 threads -> one partial per block (deterministic)
    for (int off = 32; off; off >>= 1) acc += __shfl_down(acc, off, 64);
    __shared__ float wsum[4];
    int lane = threadIdx.x & 63, wid = threadIdx.x >> 6;
    if (lane == 0) wsum[wid] = acc;
    __syncthreads();
    if (threadIdx.x == 0) {
        float s = wsum[0] + wsum[1] + wsum[2] + wsum[3];
        partials[(size_t)(b0 + bz) * 512 + DHALF * 256 + blockIdx.x] = (double)s;
    }
}

__global__ void finalize(const double* __restrict__ partials, float* __restrict__ out, int n) {
    __shared__ double sh[256];
    double s = 0.0;
    for (int i = threadIdx.x; i < n; i += 256) s += partials[i];
    sh[threadIdx.x] = s;
    __syncthreads();
    for (int stride = 128; stride; stride >>= 1) {
        if (threadIdx.x < stride) sh[threadIdx.x] += sh[threadIdx.x + stride];
        __syncthreads();
    }
    if (threadIdx.x == 0) out[0] = 1.0f - (float)(sh[0] / (double)NTOT);
}

extern "C" void kernel_launch(void* const* d_in, const int* in_sizes, int n_in,
                              void* d_out, int out_size, void* d_ws, size_t ws_size,
                              hipStream_t stream) {
    const float* x  = (const float*)d_in[0];
    const float* y  = (const float*)d_in[1];
    const float* k3 = (const float*)d_in[2];
    float* out = (float*)d_out;

    char* ws = (char*)d_ws;
    float*   w11      = (float*)ws;
    double*  partials = (double*)(ws + 64);
    char*    fields   = ws + 16640;

    const size_t perBatch = (size_t)10 * VOL;   // packed fp16 fields per batch (bytes)
    const bool all4 = ws_size >= 16640 + 4 * perBatch;

    init_weights<<<1, 64, 0, stream>>>(k3, w11);

    if (all4) {
        blur_hw      <<<dim3(4, 16, 256), 256, 0, stream>>>(x, y, w11, fields, 0);
        dconv_ssim<0><<<dim3(256, 4),     256, 0, stream>>>(fields, w11, partials, 0);
        dconv_ssim<1><<<dim3(256, 4),     256, 0, stream>>>(fields, w11, partials, 0);
    } else {
        for (int b = 0; b < 4; ++b) {
            blur_hw      <<<dim3(4, 16, 64), 256, 0, stream>>>(x, y, w11, fields, b);
            dconv_ssim<0><<<dim3(256, 1),    256, 0, stream>>>(fields, w11, partials, b);
            dconv_ssim<1><<<dim3(256, 1),    256, 0, stream>>>(fields, w11, partials, b);
        }
    }

    finalize<<<1, 256, 0, stream>>>(partials, out, 2048);
}